// Round 6
// baseline (96.041 us; speedup 1.0000x reference)
//
#include <hip/hip_runtime.h>
#include <math.h>

// CapsuleLayer dynamic routing. B=256, IN=1152, K=8, J=10, D=16, 3 passes.
//
// prep_all : W -> wht bf16 [i][jd][k] (k,d transposed), x -> xht bf16 [i][b][k].
// caps_pass<P>: grid (128 i-slices x 4 b-groups), 256 thr = 4 waves.
//   Block covers 9 i x 64 b. wht/xht slabs staged to LDS (coalesced uint4),
//   wave w owns b-tile w (16 b). Per i: 10x mfma_f32_16x16x32_bf16
//   (A = W-tile [16jd x 8k pad32] from LDS, B = x [8k x 16b] from LDS).
//   C layout: b = lane&15, d = (lane>>4)*4+reg, j = tile (HW-verified map).
//   Logit = 4 in-lane FMA + shfl_xor 16/32; softmax in-lane over 10 j;
//   s accumulates in regs; waves store disjoint b-tiles (no reduce).
// k_squash<P>: reduce 128 slabs + squash -> vdot / out.
// Algebra: logits at pass t = (sum of previous v)·u_hat; pass 0 c = 0.1.

typedef float f32x4 __attribute__((ext_vector_type(4)));
typedef short bf16x8 __attribute__((ext_vector_type(8)));

#define B_TOT 256
#define IN_CAPS 1152
#define OUT_CAPS 10
#define OUT_DIM 16
#define JD 160

#define NSLICE 128
#define IPB 9              // i per block (per wave, all 9)
#define WSLAB4 (IPB * 160) // 1440 uint4
#define XSLAB4 (IPB * 64)  // 576 uint4

#define WHT_BYTES (1152ull * 160 * 8 * 2)                 // 2,949,120
#define XHT_BYTES (1152ull * 256 * 8 * 2)                 // 4,718,592
#define SP_BYTES  ((size_t)NSLICE * B_TOT * JD * 4)       // 20,971,520
#define VD_BYTES  ((size_t)B_TOT * JD * 4)                // 163,840
#define WS_NEED   (WHT_BYTES + XHT_BYTES + SP_BYTES + VD_BYTES)

static __device__ __forceinline__ unsigned f2bf(float f) {
    unsigned u = __float_as_uint(f);
    return (u + 0x7FFFu + ((u >> 16) & 1u)) >> 16;
}

// merged prep: blocks [0,2880) -> wht, [2880, 7488) -> xht
#define PW_BLOCKS 2880
#define PX_BLOCKS 4608
__global__ __launch_bounds__(256)
void prep_all(const float* __restrict__ x, const float* __restrict__ W,
              unsigned* __restrict__ whu, unsigned* __restrict__ xhu) {
    const int bid = blockIdx.x;
    if (bid < PW_BLOCKS) {
        // wht[i][jd][k] <- W[i][j][k][d], packed k-pairs
        const int g = bid * 256 + threadIdx.x;          // < 737280
        const int i = g / 640, p = g % 640;
        const int jd = p >> 2, kk = (p & 3) * 2;
        const int j = jd >> 4, d = jd & 15;
        const int base = i * 1280 + j * 128 + d;
        const unsigned lo = f2bf(W[base + kk * 16]);
        const unsigned hi = f2bf(W[base + (kk + 1) * 16]);
        whu[g] = lo | (hi << 16);
    } else {
        // xht[i][b][k] <- x[b][i][k], packed k-pairs
        const int g = (bid - PW_BLOCKS) * 256 + threadIdx.x;   // < 1179648
        const int i = g / 1024, r = g % 1024;
        const int b = r >> 2, kk = (r & 3) * 2;
        const int in = b * 9216 + i * 8 + kk;
        const unsigned lo = f2bf(x[in]);
        const unsigned hi = f2bf(x[in + 1]);
        xhu[g] = lo | (hi << 16);
    }
}

template<int PASS>
__global__ __launch_bounds__(256, 2)
void caps_pass(const unsigned short* __restrict__ wht,
               const unsigned short* __restrict__ xht,
               const float* __restrict__ vdot,
               float* __restrict__ s_part) {
    __shared__ __align__(16) unsigned short wsl[WSLAB4 * 8];  // 23,040 B
    __shared__ __align__(16) unsigned short xsl[XSLAB4 * 8];  //  9,216 B

    const int t  = threadIdx.x;
    const int l  = t & 63;
    const int w  = t >> 6;            // wave 0..3 = b-tile
    const int m  = l & 15;            // b within tile / A-row / C-col
    const int q  = l >> 4;            // k-slot group (in) / d-quad (out)
    const int sl = blockIdx.x;        // i-slice 0..127
    const int i0 = sl * IPB;
    const int b0 = blockIdx.y * 64;
    const int bg = b0 + w * 16 + m;   // this lane's batch

    // ---- stage wht slab (contiguous) ----
    {
        const uint4* src = (const uint4*)(wht + (size_t)i0 * 1280);
        uint4* dst = (uint4*)wsl;
        for (int c = t; c < WSLAB4; c += 256) dst[c] = src[c];
    }
    // ---- stage xht slab (contiguous per i) ----
    {
        uint4* dst = (uint4*)xsl;
        for (int c = t; c < XSLAB4; c += 256) {
            const int il = c >> 6, cc = c & 63;
            dst[c] = *((const uint4*)(xht + ((size_t)(i0 + il) * B_TOT + b0) * 8) + cc);
        }
    }

    // vdot fragments (i-invariant): vd[j][r] = vdot[bg][j][q*4+r]
    f32x4 vd[10];
    if (PASS > 0) {
        #pragma unroll
        for (int jt = 0; jt < 10; ++jt)
            vd[jt] = *(const f32x4*)(vdot + (size_t)bg * JD + jt * 16 + q * 4);
    }

    f32x4 s[10];
    #pragma unroll
    for (int jt = 0; jt < 10; ++jt) s[jt] = (f32x4){0.f, 0.f, 0.f, 0.f};

    __syncthreads();

    const bf16x8 zfrag = {0, 0, 0, 0, 0, 0, 0, 0};

    #pragma unroll 1
    for (int il = 0; il < IPB; ++il) {
        // B-frag: q==0 lanes hold x[bg][i][k=0..7]; k>=8 zero-padded
        bf16x8 xb = zfrag;
        if (q == 0)
            xb = *(const bf16x8*)(xsl + ((il * 64) + w * 16 + m) * 8);

        f32x4 u[10];
        #pragma unroll
        for (int jt = 0; jt < 10; ++jt) {
            bf16x8 af = zfrag;   // A-frag: W[i][jt*16+m][k=0..7]
            if (q == 0)
                af = *(const bf16x8*)(wsl + ((il * 160) + jt * 16 + m) * 8);
            u[jt] = __builtin_amdgcn_mfma_f32_16x16x32_bf16(
                        af, xb, (f32x4){0.f, 0.f, 0.f, 0.f}, 0, 0, 0);
        }

        if (PASS == 0) {
            #pragma unroll
            for (int jt = 0; jt < 10; ++jt) s[jt] += 0.1f * u[jt];
        } else {
            // logit[j] = sum_d vd.u : in-lane dot4, reduce lanes {l, l^16, l^32}
            float L[10];
            #pragma unroll
            for (int jt = 0; jt < 10; ++jt) {
                const f32x4 p = vd[jt] * u[jt];
                float e = (p.x + p.y) + (p.z + p.w);
                e += __shfl_xor(e, 16);
                e += __shfl_xor(e, 32);
                L[jt] = e;
            }
            float mx = L[0];
            #pragma unroll
            for (int jt = 1; jt < 10; ++jt) mx = fmaxf(mx, L[jt]);
            float Z = 0.f;
            #pragma unroll
            for (int jt = 0; jt < 10; ++jt) { L[jt] = __expf(L[jt] - mx); Z += L[jt]; }
            const float inv = 1.0f / Z;
            #pragma unroll
            for (int jt = 0; jt < 10; ++jt) s[jt] += (L[jt] * inv) * u[jt];
        }
    }

    // waves own disjoint b-tiles: store directly (q-quads make 64B granules)
    {
        float* sp = s_part + ((size_t)sl * B_TOT + bg) * JD;
        #pragma unroll
        for (int jt = 0; jt < 10; ++jt)
            *(f32x4*)(sp + jt * 16 + q * 4) = s[jt];
    }
}

template<int PASS>
__global__ __launch_bounds__(256)
void k_squash(const float* __restrict__ s_part,
              float* __restrict__ vdot, float* __restrict__ out) {
    const int e = blockIdx.x * 256 + threadIdx.x;    // < 40960
    float s = 0.f;
    #pragma unroll 8
    for (int p = 0; p < NSLICE; ++p)
        s += s_part[(size_t)p * (B_TOT * JD) + e];

    float t = s * s;
    t += __shfl_xor(t, 1);
    t += __shfl_xor(t, 2);
    t += __shfl_xor(t, 4);
    t += __shfl_xor(t, 8);
    const float scale = t / (1.0f + t) / sqrtf(t + 1e-7f);
    const float v = scale * s;

    if (PASS == 0)      vdot[e] = v;
    else if (PASS == 1) vdot[e] += v;
    else                out[e] = v;
}

// ---------- fallback: round-1 fused kernel (ws too small; shouldn't happen) ----------
#define FB_NGROUPS 32
#define FB_THREADS (FB_NGROUPS * OUT_DIM)
#define FB_ITERS (IN_CAPS / FB_NGROUPS)
__global__ __launch_bounds__(FB_THREADS)
void caps_routing_kernel(const float* __restrict__ x, const float* __restrict__ W,
                         float* __restrict__ out) {
    __shared__ __align__(16) float xsf[IN_CAPS * 8];
    __shared__ float sredf[FB_NGROUPS * JD];
    __shared__ float vdot_lds[JD];
    const int b = blockIdx.x, tid = threadIdx.x;
    const int g = tid >> 4, d = tid & 15;
    {
        const float4* xg = reinterpret_cast<const float4*>(x + (size_t)b * IN_CAPS * 8);
        float4* xl = reinterpret_cast<float4*>(xsf);
        for (int t = tid; t < IN_CAPS * 2; t += FB_THREADS) xl[t] = xg[t];
    }
    __syncthreads();
    for (int pass = 0; pass < 3; ++pass) {
        float vdot_reg[OUT_CAPS];
        if (pass > 0) {
            #pragma unroll
            for (int j = 0; j < OUT_CAPS; ++j) vdot_reg[j] = vdot_lds[j * OUT_DIM + d];
        }
        float s_loc[OUT_CAPS];
        #pragma unroll
        for (int j = 0; j < OUT_CAPS; ++j) s_loc[j] = 0.f;
        for (int it = 0; it < FB_ITERS; ++it) {
            const int i = it * FB_NGROUPS + g;
            float xk[8];
            {
                const float4* xr = reinterpret_cast<const float4*>(xsf + i * 8);
                float4 a0 = xr[0], a1 = xr[1];
                xk[0]=a0.x; xk[1]=a0.y; xk[2]=a0.z; xk[3]=a0.w;
                xk[4]=a1.x; xk[5]=a1.y; xk[6]=a1.z; xk[7]=a1.w;
            }
            const float* wpf = W + (size_t)i * 1280 + d;
            float u[OUT_CAPS];
            #pragma unroll
            for (int j = 0; j < OUT_CAPS; ++j) {
                float acc = 0.f;
                #pragma unroll
                for (int k = 0; k < 8; ++k) acc = fmaf(xk[k], wpf[j * 128 + k * OUT_DIM], acc);
                u[j] = acc;
            }
            if (pass == 0) {
                #pragma unroll
                for (int j = 0; j < OUT_CAPS; ++j) s_loc[j] = fmaf(0.1f, u[j], s_loc[j]);
            } else {
                float logit[OUT_CAPS];
                #pragma unroll
                for (int j = 0; j < OUT_CAPS; ++j) {
                    float t2 = vdot_reg[j] * u[j];
                    t2 += __shfl_xor(t2, 1); t2 += __shfl_xor(t2, 2);
                    t2 += __shfl_xor(t2, 4); t2 += __shfl_xor(t2, 8);
                    logit[j] = t2;
                }
                float m = logit[0];
                #pragma unroll
                for (int j = 1; j < OUT_CAPS; ++j) m = fmaxf(m, logit[j]);
                float Z = 0.f, e[OUT_CAPS];
                #pragma unroll
                for (int j = 0; j < OUT_CAPS; ++j) { e[j] = expf(logit[j] - m); Z += e[j]; }
                const float invZ = 1.0f / Z;
                #pragma unroll
                for (int j = 0; j < OUT_CAPS; ++j) s_loc[j] = fmaf(e[j] * invZ, u[j], s_loc[j]);
            }
        }
        #pragma unroll
        for (int j = 0; j < OUT_CAPS; ++j) sredf[g * JD + j * OUT_DIM + d] = s_loc[j];
        __syncthreads();
        if (tid < JD) {
            float sv = 0.f;
            #pragma unroll 8
            for (int gg = 0; gg < FB_NGROUPS; ++gg) sv += sredf[gg * JD + tid];
            float t2 = sv * sv;
            t2 += __shfl_xor(t2, 1); t2 += __shfl_xor(t2, 2);
            t2 += __shfl_xor(t2, 4); t2 += __shfl_xor(t2, 8);
            const float scale = t2 / (1.0f + t2) / sqrtf(t2 + 1e-7f);
            const float v = scale * sv;
            if (pass == 2) out[(size_t)b * JD + tid] = v;
            else vdot_lds[tid] = (pass == 0) ? v : (vdot_lds[tid] + v);
        }
        __syncthreads();
    }
}

extern "C" void kernel_launch(void* const* d_in, const int* in_sizes, int n_in,
                              void* d_out, int out_size, void* d_ws, size_t ws_size,
                              hipStream_t stream) {
    const float* x = (const float*)d_in[0];
    const float* W = (const float*)d_in[1];
    float* out = (float*)d_out;

    if (ws_size >= WS_NEED) {
        unsigned short* wht = (unsigned short*)d_ws;
        unsigned short* xht = (unsigned short*)((char*)d_ws + WHT_BYTES);
        float* s_part = (float*)((char*)d_ws + WHT_BYTES + XHT_BYTES);
        float* vdot   = (float*)((char*)d_ws + WHT_BYTES + XHT_BYTES + SP_BYTES);

        prep_all<<<PW_BLOCKS + PX_BLOCKS, 256, 0, stream>>>(x, W, (unsigned*)wht, (unsigned*)xht);

        const dim3 gR(NSLICE, 4);
        const int gSQ = (B_TOT * JD) / 256;   // 160

        caps_pass<0><<<gR, 256, 0, stream>>>(wht, xht, vdot, s_part);
        k_squash<0><<<gSQ, 256, 0, stream>>>(s_part, vdot, out);
        caps_pass<1><<<gR, 256, 0, stream>>>(wht, xht, vdot, s_part);
        k_squash<1><<<gSQ, 256, 0, stream>>>(s_part, vdot, out);
        caps_pass<2><<<gR, 256, 0, stream>>>(wht, xht, vdot, s_part);
        k_squash<2><<<gSQ, 256, 0, stream>>>(s_part, vdot, out);
    } else {
        caps_routing_kernel<<<B_TOT, FB_THREADS, 0, stream>>>(x, W, out);
    }
}